// Round 12
// baseline (38.110 us; speedup 1.0000x reference)
//
#include <hip/hip_runtime.h>
#include <hip/hip_bf16.h>

#define B    64
#define T    4096
#define V    64
#define NQ   64      // NGRAN * NGLIMPSE
#define NHID 2048
#define KDIM 4096    // V * NQ
#define FAN  4097    // KDIM + 1 (l_t column)

#define NT     16    // h rows per gemm block (one MFMA n-tile)
#define SPLITS 8     // K-split across gemm blocks

typedef __attribute__((ext_vector_type(8))) short bf16x8;
typedef __attribute__((ext_vector_type(4))) float f32x4;

static __device__ __forceinline__ short f2bf(float x) {
    union { float f; unsigned u; } c; c.f = x;
    unsigned r = c.u + 0x7fff + ((c.u >> 16) & 1);   // RNE
    return (short)(r >> 16);
}

// ---------------------------------------------------------------------------
// Kernel 1: glimpse interpolation (unchanged). grid = (B, NQ), block = 64
// (lane = v). Writes g_bf16[b][k] (k=v*NQ+q), out2, zeroes out[] slice.
// ---------------------------------------------------------------------------
__global__ __launch_bounds__(64) void glimpse_kernel(
    const float* __restrict__ vals, const float* __restrict__ time_,
    const int* __restrict__ masks, const float* __restrict__ l_t,
    unsigned short* __restrict__ g_bf, float* __restrict__ out2,
    float* __restrict__ out)
{
    const int b = blockIdx.x;
    const int q = blockIdx.y;
    const int v = threadIdx.x;

    if (v < 32) out[(size_t)b * NHID + q * 32 + v] = 0.0f;

    const float* t = time_ + (size_t)b * T;
    const float tmax = t[T - 1];          // times sorted ascending

    const int   j = q & 31;
    const float s = (q < 32) ? 1.0f : 5.0f;
    const float a = 0.5f * 0.1f * s;      // gwidth*s/2
    const float step = (2.0f * a) / 31.0f;
    float lin = (j == 31) ? a : (-a + step * (float)j);
    const float r = (lin + l_t[b]) * tmax;

    // binary search: p = first index with t[p] > r  (wave-uniform)
    int lo = 0, hi = T;
    while (lo < hi) {
        int mid = (lo + hi) >> 1;
        if (t[mid] > r) hi = mid; else lo = mid + 1;
    }
    const int p = lo;

    const int*   m  = masks + (size_t)b * T * V + v;
    const float* vv = vals  + (size_t)b * T * V + v;

    int i0 = -1;
    for (int i = p - 1; i >= 0; --i) {
        if (m[(size_t)i * V] != 0) { i0 = i; break; }
    }
    int i1 = -1;
    for (int i = p; i < T; ++i) {
        if (m[(size_t)i * V] != 0) { i1 = i; break; }
    }

    float y;
    if (i0 < 0 && i1 < 0) {
        y = 0.0f;
    } else if (i0 < 0) {
        y = vv[(size_t)i1 * V];
    } else if (i1 < 0) {
        y = vv[(size_t)i0 * V];
    } else {
        float t0 = t[i0], t1 = t[i1];
        float v0 = vv[(size_t)i0 * V], v1 = vv[(size_t)i1 * V];
        float den = (t1 > t0) ? (t1 - t0) : 1.0f;
        float w = (r - t0) / den;
        w = fminf(fmaxf(w, 0.0f), 1.0f);
        y = v0 + w * (v1 - v0);
    }

    const int k = v * NQ + q;
    g_bf[(size_t)b * KDIM + k] = (unsigned short)f2bf(y);
    if (k == KDIM / 2) out2[b] = y;             // g[:, 2048], fp32
}

// ---------------------------------------------------------------------------
// Kernel 2: MFMA GEMM — DIAGNOSTIC: mrep=8 (runtime) so the warm marginal
// pass cost = (total - 32.2)/7 and the gemm's PMC row finally surfaces in
// top-5 (past the ~39us harness-fill cutoff). acc accumulates 8x, exact
// x0.125 rescale. Structure otherwise identical to R11.
// grid = (NHID/NT, SPLITS) = 1024 blocks x 256 thr (4 waves).
// ---------------------------------------------------------------------------
__global__ __launch_bounds__(256) void gemm_mfma(
    const unsigned short* __restrict__ g_bf, const float* __restrict__ l_t,
    const float* __restrict__ W, const float* __restrict__ bias,
    float* __restrict__ out, int mrep, float scale)
{
    __shared__ float part[4][B][NT];            // 16 KB
    const int lane = threadIdx.x & 63;
    const int wave = threadIdx.x >> 6;
    const int l15  = lane & 15;                 // n (h offset) for B, m for A
    const int lk   = lane >> 4;                 // k-group 0..3
    const int hbase = blockIdx.x * NT;
    const int kbase = blockIdx.y * (KDIM / SPLITS) + wave * (KDIM / SPLITS / 4);

    const float* wrow = W + (size_t)(hbase + l15) * FAN;   // this lane's W row

    f32x4 acc[4];
    #pragma unroll
    for (int mt = 0; mt < 4; ++mt) acc[mt] = (f32x4){0.f, 0.f, 0.f, 0.f};

    for (int rep = 0; rep < mrep; ++rep) {
        #pragma unroll
        for (int ks = 0; ks < KDIM / SPLITS / 4; ks += 32) {
            const int k = kbase + ks + lk * 8;  // this lane's 8 consecutive k

            // B fragment: W[hbase+l15][k .. k+7] fp32 -> bf16
            bf16x8 bfrag;
            #pragma unroll
            for (int e = 0; e < 8; ++e) bfrag[e] = f2bf(wrow[k + e]);

            // A fragments: g[mt*16+l15][k .. k+7] already bf16, 16B aligned
            #pragma unroll
            for (int mt = 0; mt < 4; ++mt) {
                const bf16x8 afrag =
                    *(const bf16x8*)(g_bf + (size_t)(mt * 16 + l15) * KDIM + k);
                acc[mt] = __builtin_amdgcn_mfma_f32_16x16x32_bf16(afrag, bfrag, acc[mt], 0, 0, 0);
            }
        }
        asm volatile("" ::: "memory");   // keep per-pass schedule; force re-loads
    }

    // runtime rescale (host passes scale = 1/mrep)
    #pragma unroll
    for (int mt = 0; mt < 4; ++mt) acc[mt] = acc[mt] * scale;

    // C/D layout: col = lane&15 (h offset), row = (lane>>4)*4 + reg (b in tile)
    #pragma unroll
    for (int mt = 0; mt < 4; ++mt) {
        #pragma unroll
        for (int rreg = 0; rreg < 4; ++rreg) {
            const int b = mt * 16 + lk * 4 + rreg;
            part[wave][b][l15] = acc[mt][rreg];
        }
    }
    __syncthreads();

    for (int o = threadIdx.x; o < B * NT; o += 256) {
        const int b = o >> 4, hoff = o & 15;
        const int h = hbase + hoff;
        float v = part[0][b][hoff] + part[1][b][hoff]
                + part[2][b][hoff] + part[3][b][hoff];
        if (blockIdx.y == 0)
            v += bias[h] + l_t[b] * W[(size_t)h * FAN + KDIM];
        atomicAdd(&out[(size_t)b * NHID + h], v);
    }
}

extern "C" void kernel_launch(void* const* d_in, const int* in_sizes, int n_in,
                              void* d_out, int out_size, void* d_ws, size_t ws_size,
                              hipStream_t stream) {
    const float* vals  = (const float*)d_in[0];
    const float* time_ = (const float*)d_in[1];
    const int*   masks = (const int*)d_in[2];
    // d_in[3] = lengths (all == T, unused)
    const float* l_t   = (const float*)d_in[4];
    const float* W     = (const float*)d_in[5];
    const float* bias  = (const float*)d_in[6];

    float* out  = (float*)d_out;                 // grep [B, NHID]
    float* out2 = out + (size_t)B * NHID;        // g[:, 2048]  [B]
    unsigned short* g_bf = (unsigned short*)d_ws; // bf16 [B][KDIM] = 512 KB

    dim3 g1(B, NQ);
    glimpse_kernel<<<g1, 64, 0, stream>>>(vals, time_, masks, l_t, g_bf, out2, out);

    dim3 g2(NHID / NT, SPLITS);
    gemm_mfma<<<g2, 256, 0, stream>>>(g_bf, l_t, W, bias, out, 8, 0.125f);
}

// Round 13
// 34.828 us; speedup vs baseline: 1.0942x; 1.0942x over previous
//
#include <hip/hip_runtime.h>
#include <hip/hip_bf16.h>

#define B    64
#define T    4096
#define V    64
#define NQ   64      // NGRAN * NGLIMPSE
#define NHID 2048
#define KDIM 4096    // V * NQ
#define FAN  4097    // KDIM + 1 (l_t column)

#define NT     16    // h rows per gemm block (one MFMA n-tile)
#define SPLITS 8     // K-split across gemm blocks

typedef __attribute__((ext_vector_type(8))) short bf16x8;
typedef __attribute__((ext_vector_type(4))) float f32x4;

static __device__ __forceinline__ short f2bf(float x) {
    union { float f; unsigned u; } c; c.f = x;
    unsigned r = c.u + 0x7fff + ((c.u >> 16) & 1);   // RNE
    return (short)(r >> 16);
}

// ---------------------------------------------------------------------------
// Kernel 1: glimpse interpolation (~6 us). grid = (B, NQ), block = 64
// (lane = v). Writes g_bf16[b][k] (k=v*NQ+q) and out2. No out-zeroing
// anymore (atomic tail removed).
// ---------------------------------------------------------------------------
__global__ __launch_bounds__(64) void glimpse_kernel(
    const float* __restrict__ vals, const float* __restrict__ time_,
    const int* __restrict__ masks, const float* __restrict__ l_t,
    unsigned short* __restrict__ g_bf, float* __restrict__ out2)
{
    const int b = blockIdx.x;
    const int q = blockIdx.y;
    const int v = threadIdx.x;

    const float* t = time_ + (size_t)b * T;
    const float tmax = t[T - 1];          // times sorted ascending

    const int   j = q & 31;
    const float s = (q < 32) ? 1.0f : 5.0f;
    const float a = 0.5f * 0.1f * s;      // gwidth*s/2
    const float step = (2.0f * a) / 31.0f;
    float lin = (j == 31) ? a : (-a + step * (float)j);
    const float r = (lin + l_t[b]) * tmax;

    // binary search: p = first index with t[p] > r  (wave-uniform)
    int lo = 0, hi = T;
    while (lo < hi) {
        int mid = (lo + hi) >> 1;
        if (t[mid] > r) hi = mid; else lo = mid + 1;
    }
    const int p = lo;

    const int*   m  = masks + (size_t)b * T * V + v;
    const float* vv = vals  + (size_t)b * T * V + v;

    int i0 = -1;
    for (int i = p - 1; i >= 0; --i) {
        if (m[(size_t)i * V] != 0) { i0 = i; break; }
    }
    int i1 = -1;
    for (int i = p; i < T; ++i) {
        if (m[(size_t)i * V] != 0) { i1 = i; break; }
    }

    float y;
    if (i0 < 0 && i1 < 0) {
        y = 0.0f;
    } else if (i0 < 0) {
        y = vv[(size_t)i1 * V];
    } else if (i1 < 0) {
        y = vv[(size_t)i0 * V];
    } else {
        float t0 = t[i0], t1 = t[i1];
        float v0 = vv[(size_t)i0 * V], v1 = vv[(size_t)i1 * V];
        float den = (t1 > t0) ? (t1 - t0) : 1.0f;
        float w = (r - t0) / den;
        w = fminf(fmaxf(w, 0.0f), 1.0f);
        y = v0 + w * (v1 - v0);
    }

    const int k = v * NQ + q;
    g_bf[(size_t)b * KDIM + k] = (unsigned short)f2bf(y);
    if (k == KDIM / 2) out2[b] = y;             // g[:, 2048], fp32
}

// ---------------------------------------------------------------------------
// Kernel 2: MFMA GEMM — K-loop unchanged from R11 (warm pass measured at
// 0.84 us). TAIL REPLACED: no atomics; LDS-reduce 4 waves then plain stores
// of the block's [B][NT] partial into pws[s][b][h]. No out coupling.
// grid = (NHID/NT, SPLITS) = 1024 blocks x 256 thr (4 waves).
// ---------------------------------------------------------------------------
__global__ __launch_bounds__(256) void gemm_mfma(
    const unsigned short* __restrict__ g_bf,
    const float* __restrict__ W, float* __restrict__ pws,
    int mrep, float scale)
{
    __shared__ float part[4][B][NT];            // 16 KB
    const int lane = threadIdx.x & 63;
    const int wave = threadIdx.x >> 6;
    const int l15  = lane & 15;                 // n (h offset) for B, m for A
    const int lk   = lane >> 4;                 // k-group 0..3
    const int hbase = blockIdx.x * NT;
    const int s     = blockIdx.y;
    const int kbase = s * (KDIM / SPLITS) + wave * (KDIM / SPLITS / 4);

    const float* wrow = W + (size_t)(hbase + l15) * FAN;   // this lane's W row

    f32x4 acc[4];
    #pragma unroll
    for (int mt = 0; mt < 4; ++mt) acc[mt] = (f32x4){0.f, 0.f, 0.f, 0.f};

    for (int rep = 0; rep < mrep; ++rep) {
        #pragma unroll
        for (int ks = 0; ks < KDIM / SPLITS / 4; ks += 32) {
            const int k = kbase + ks + lk * 8;  // this lane's 8 consecutive k

            // B fragment: W[hbase+l15][k .. k+7] fp32 -> bf16
            bf16x8 bfrag;
            #pragma unroll
            for (int e = 0; e < 8; ++e) bfrag[e] = f2bf(wrow[k + e]);

            // A fragments: g[mt*16+l15][k .. k+7] already bf16, 16B aligned
            #pragma unroll
            for (int mt = 0; mt < 4; ++mt) {
                const bf16x8 afrag =
                    *(const bf16x8*)(g_bf + (size_t)(mt * 16 + l15) * KDIM + k);
                acc[mt] = __builtin_amdgcn_mfma_f32_16x16x32_bf16(afrag, bfrag, acc[mt], 0, 0, 0);
            }
        }
        asm volatile("" ::: "memory");
    }

    #pragma unroll
    for (int mt = 0; mt < 4; ++mt) acc[mt] = acc[mt] * scale;

    // C/D layout: col = lane&15 (h offset), row = (lane>>4)*4 + reg (b in tile)
    #pragma unroll
    for (int mt = 0; mt < 4; ++mt) {
        #pragma unroll
        for (int rreg = 0; rreg < 4; ++rreg) {
            const int b = mt * 16 + lk * 4 + rreg;
            part[wave][b][l15] = acc[mt][rreg];
        }
    }
    __syncthreads();

    // plain stores: pws[s][b][hbase+hoff]
    for (int o = threadIdx.x; o < B * NT; o += 256) {
        const int b = o >> 4, hoff = o & 15;
        const float v = part[0][b][hoff] + part[1][b][hoff]
                      + part[2][b][hoff] + part[3][b][hoff];
        pws[((size_t)s * B + b) * NHID + hbase + hoff] = v;
    }
}

// ---------------------------------------------------------------------------
// Kernel 3: reduce 8 split-partials + bias + l_t column -> out.
// grid = B*NHID/256 = 512 blocks x 256 thr. All loads/stores coalesced
// (per-plane stride B*NHID); W l_t-column reads cached (2048 distinct).
// ---------------------------------------------------------------------------
__global__ __launch_bounds__(256) void reduce_kernel(
    const float* __restrict__ pws, const float* __restrict__ l_t,
    const float* __restrict__ W, const float* __restrict__ bias,
    float* __restrict__ out)
{
    const int idx = blockIdx.x * 256 + threadIdx.x;   // b*NHID + h
    const int b = idx >> 11;                          // / NHID
    const int h = idx & (NHID - 1);
    float v = 0.0f;
    #pragma unroll
    for (int s = 0; s < SPLITS; ++s)
        v += pws[(size_t)s * (B * NHID) + idx];
    v += bias[h] + l_t[b] * W[(size_t)h * FAN + KDIM];
    out[idx] = v;
}

extern "C" void kernel_launch(void* const* d_in, const int* in_sizes, int n_in,
                              void* d_out, int out_size, void* d_ws, size_t ws_size,
                              hipStream_t stream) {
    const float* vals  = (const float*)d_in[0];
    const float* time_ = (const float*)d_in[1];
    const int*   masks = (const int*)d_in[2];
    // d_in[3] = lengths (all == T, unused)
    const float* l_t   = (const float*)d_in[4];
    const float* W     = (const float*)d_in[5];
    const float* bias  = (const float*)d_in[6];

    float* out  = (float*)d_out;                 // grep [B, NHID]
    float* out2 = out + (size_t)B * NHID;        // g[:, 2048]  [B]
    unsigned short* g_bf = (unsigned short*)d_ws;           // 512 KB
    float* pws = (float*)((char*)d_ws + (1 << 20));         // 4 MB partials

    dim3 g1(B, NQ);
    glimpse_kernel<<<g1, 64, 0, stream>>>(vals, time_, masks, l_t, g_bf, out2);

    dim3 g2(NHID / NT, SPLITS);
    gemm_mfma<<<g2, 256, 0, stream>>>(g_bf, W, pws, 1, 1.0f);

    reduce_kernel<<<(B * NHID) / 256, 256, 0, stream>>>(pws, l_t, W, bias, out);
}

// Round 14
// 31.159 us; speedup vs baseline: 1.2231x; 1.1178x over previous
//
#include <hip/hip_runtime.h>
#include <hip/hip_bf16.h>

#define B    64
#define T    4096
#define V    64
#define NQ   64      // NGRAN * NGLIMPSE
#define NHID 2048
#define KDIM 4096    // V * NQ
#define FAN  4097    // KDIM + 1 (l_t column)

#define NT     32    // h rows per gemm block (2 MFMA n-tiles)
#define SPLITS 16    // K-split across gemm blocks
#define KC     (KDIM / SPLITS)   // 256 k per block
#define LDA    (KC + 8)          // LDS row stride (bf16): 528B -> ~2-way banks

typedef __attribute__((ext_vector_type(8))) short bf16x8;
typedef __attribute__((ext_vector_type(4))) float f32x4;

static __device__ __forceinline__ short f2bf(float x) {
    union { float f; unsigned u; } c; c.f = x;
    unsigned r = c.u + 0x7fff + ((c.u >> 16) & 1);   // RNE
    return (short)(r >> 16);
}

// ---------------------------------------------------------------------------
// Kernel 1: glimpse interpolation (~5-6 us measured). grid = (B, NQ),
// block = 64 (lane = v). Writes g_bf16[b][k] (k=v*NQ+q), out2, and zeroes
// out[] slice for the gemm's atomicAdd (stream-ordered before gemm).
// ---------------------------------------------------------------------------
__global__ __launch_bounds__(64) void glimpse_kernel(
    const float* __restrict__ vals, const float* __restrict__ time_,
    const int* __restrict__ masks, const float* __restrict__ l_t,
    unsigned short* __restrict__ g_bf, float* __restrict__ out2,
    float* __restrict__ out)
{
    const int b = blockIdx.x;
    const int q = blockIdx.y;
    const int v = threadIdx.x;

    if (v < 32) out[(size_t)b * NHID + q * 32 + v] = 0.0f;

    const float* t = time_ + (size_t)b * T;
    const float tmax = t[T - 1];          // times sorted ascending

    const int   j = q & 31;
    const float s = (q < 32) ? 1.0f : 5.0f;
    const float a = 0.5f * 0.1f * s;      // gwidth*s/2
    const float step = (2.0f * a) / 31.0f;
    float lin = (j == 31) ? a : (-a + step * (float)j);
    const float r = (lin + l_t[b]) * tmax;

    // binary search: p = first index with t[p] > r  (wave-uniform)
    int lo = 0, hi = T;
    while (lo < hi) {
        int mid = (lo + hi) >> 1;
        if (t[mid] > r) hi = mid; else lo = mid + 1;
    }
    const int p = lo;

    const int*   m  = masks + (size_t)b * T * V + v;
    const float* vv = vals  + (size_t)b * T * V + v;

    int i0 = -1;
    for (int i = p - 1; i >= 0; --i) {
        if (m[(size_t)i * V] != 0) { i0 = i; break; }
    }
    int i1 = -1;
    for (int i = p; i < T; ++i) {
        if (m[(size_t)i * V] != 0) { i1 = i; break; }
    }

    float y;
    if (i0 < 0 && i1 < 0) {
        y = 0.0f;
    } else if (i0 < 0) {
        y = vv[(size_t)i1 * V];
    } else if (i1 < 0) {
        y = vv[(size_t)i0 * V];
    } else {
        float t0 = t[i0], t1 = t[i1];
        float v0 = vv[(size_t)i0 * V], v1 = vv[(size_t)i1 * V];
        float den = (t1 > t0) ? (t1 - t0) : 1.0f;
        float w = (r - t0) / den;
        w = fminf(fmaxf(w, 0.0f), 1.0f);
        y = v0 + w * (v1 - v0);
    }

    const int k = v * NQ + q;
    g_bf[(size_t)b * KDIM + k] = (unsigned short)f2bf(y);
    if (k == KDIM / 2) out2[b] = y;             // g[:, 2048], fp32
}

// ---------------------------------------------------------------------------
// Kernel 2: MFMA GEMM — BOTH operands staged to LDS with fully-coalesced
// global reads (the A-side 16-row fan-out pattern, present since R3, is the
// last never-varied operand path). grid = (NHID/NT, SPLITS) = (64,16) = 1024
// blocks x 256 thr (4 waves). Per block: A-tile = g_bf[0..63][kbase..+255]
// (bf16x8 chunks, rows contiguous), W-tile = W[hbase..+31][kbase..+255]
// fp32->bf16 scalar coalesced. Wave w owns m-rows [16w,16w+16), both n-tiles,
// full 256 k -> 16 MFMAs; accs atomicAdd directly (out pre-zeroed).
// ---------------------------------------------------------------------------
__global__ __launch_bounds__(256) void gemm_mfma(
    const unsigned short* __restrict__ g_bf, const float* __restrict__ l_t,
    const float* __restrict__ W, const float* __restrict__ bias,
    float* __restrict__ out)
{
    __shared__ unsigned short alds[B][LDA];     // 33.0 KB
    __shared__ unsigned short wlds[NT][LDA];    // 16.5 KB
    const int tid  = threadIdx.x;
    const int lane = tid & 63;
    const int wave = tid >> 6;
    const int l15  = lane & 15;
    const int lk   = lane >> 4;                 // k-group 0..3
    const int hbase = blockIdx.x * NT;
    const int s     = blockIdx.y;
    const int kbase = s * KC;

    // ---- stage A: 64 rows x 256 cols bf16, 16B chunks, coalesced ----
    #pragma unroll
    for (int i = 0; i < (B * KC) / (256 * 8); ++i) {   // 8 iters
        const int c   = tid + i * 256;
        const int row = c >> 5;                 // 32 chunks per row
        const int c8  = (c & 31) << 3;
        *(bf16x8*)&alds[row][c8] =
            *(const bf16x8*)(g_bf + (size_t)row * KDIM + kbase + c8);
    }
    // ---- stage W: 32 rows x 256 cols fp32 -> bf16, scalar coalesced ----
    #pragma unroll
    for (int i = 0; i < (NT * KC) / 256; ++i) {        // 32 iters
        const int c   = tid + i * 256;
        const int row = c >> 8;                 // 256 floats per row
        const int col = c & (KC - 1);
        wlds[row][col] =
            (unsigned short)f2bf(W[(size_t)(hbase + row) * FAN + kbase + col]);
    }
    __syncthreads();

    f32x4 acc[2];
    acc[0] = (f32x4){0.f, 0.f, 0.f, 0.f};
    acc[1] = (f32x4){0.f, 0.f, 0.f, 0.f};

    #pragma unroll
    for (int ks = 0; ks < KC; ks += 32) {
        const int kl = ks + lk * 8;
        const bf16x8 afrag = *(const bf16x8*)&alds[wave * 16 + l15][kl];
        #pragma unroll
        for (int nt = 0; nt < 2; ++nt) {
            const bf16x8 bfrag = *(const bf16x8*)&wlds[nt * 16 + l15][kl];
            acc[nt] = __builtin_amdgcn_mfma_f32_16x16x32_bf16(afrag, bfrag, acc[nt], 0, 0, 0);
        }
    }

    // C/D layout: col = lane&15 (h offset), row = (lane>>4)*4 + reg (b offset)
    #pragma unroll
    for (int nt = 0; nt < 2; ++nt) {
        const int h = hbase + nt * 16 + l15;
        #pragma unroll
        for (int r = 0; r < 4; ++r) {
            const int b = wave * 16 + lk * 4 + r;
            float v = acc[nt][r];
            if (s == 0)
                v += bias[h] + l_t[b] * W[(size_t)h * FAN + KDIM];
            atomicAdd(&out[(size_t)b * NHID + h], v);
        }
    }
}

extern "C" void kernel_launch(void* const* d_in, const int* in_sizes, int n_in,
                              void* d_out, int out_size, void* d_ws, size_t ws_size,
                              hipStream_t stream) {
    const float* vals  = (const float*)d_in[0];
    const float* time_ = (const float*)d_in[1];
    const int*   masks = (const int*)d_in[2];
    // d_in[3] = lengths (all == T, unused)
    const float* l_t   = (const float*)d_in[4];
    const float* W     = (const float*)d_in[5];
    const float* bias  = (const float*)d_in[6];

    float* out  = (float*)d_out;                 // grep [B, NHID]
    float* out2 = out + (size_t)B * NHID;        // g[:, 2048]  [B]
    unsigned short* g_bf = (unsigned short*)d_ws; // bf16 [B][KDIM] = 512 KB

    dim3 g1(B, NQ);
    glimpse_kernel<<<g1, 64, 0, stream>>>(vals, time_, masks, l_t, g_bf, out2, out);

    dim3 g2(NHID / NT, SPLITS);
    gemm_mfma<<<g2, 256, 0, stream>>>(g_bf, l_t, W, bias, out);
}